// Round 16
// baseline (468.677 us; speedup 1.0000x reference)
//
#include <hip/hip_runtime.h>

#define NN 512
#define SCALE 0.35355339059327373f  /* dk^-0.5, dk=8 */
#define SMAX 6.0f                   /* fixed softmax shift (exact ratios) */

typedef short bf16x8 __attribute__((ext_vector_type(8)));
typedef float f32x4 __attribute__((ext_vector_type(4)));

static __device__ __forceinline__ unsigned short bhi16(float x) {
    return (unsigned short)(__float_as_uint(x) >> 16);
}
static __device__ __forceinline__ float bf2f(unsigned short u) {
    return __uint_as_float(((unsigned int)u) << 16);
}

// ---------------- K1: QKV projection (+ K pre-truncated to bf16) ----------
__global__ __launch_bounds__(64) void qkv_proj(const float* __restrict__ nin,
                                               const float* __restrict__ Wqkv,
                                               float* __restrict__ qkv,
                                               unsigned short* __restrict__ kbf) {
    const int r = blockIdx.x;
    const int j = threadIdx.x;
    const float* nr = nin + (size_t)r * 64;
    float a0 = 0.f, a1 = 0.f, a2 = 0.f;
#pragma unroll
    for (int d = 0; d < 64; ++d) {
        const float nv = nr[d];
        const float* wr = Wqkv + d * 192;
        a0 = fmaf(nv, wr[j], a0);
        a1 = fmaf(nv, wr[64 + j], a1);
        a2 = fmaf(nv, wr[128 + j], a2);
    }
    float* o = qkv + (size_t)r * 192;
    o[j] = a0; o[64 + j] = a1; o[128 + j] = a2;
    kbf[(size_t)r * 64 + j] = bhi16(a1);
}

__device__ __forceinline__ void gload16f(const float* g, float* l) {
    __builtin_amdgcn_global_load_lds(
        (const __attribute__((address_space(1))) unsigned int*)(g),
        (__attribute__((address_space(3))) unsigned int*)(l), 16, 0, 0);
}
#define WAITV(N) asm volatile("s_waitcnt vmcnt(" #N ")" ::: "memory")
#define BARRIER() __builtin_amdgcn_s_barrier()

// ---------------- K2: 6-blocks/CU fused chunk kernel (K in regs) ----------
// grid 8192 = (bn, chunk of 128 m-rows). 4 waves; wave owns 32 rows = 2 slabs.
// k-bijection k = a2*16 + c*8 + j on BOTH operands -> K fragment = contiguous
// 16B per lane (direct VGPR load, no K LDS). LDS 25.5 KB -> 6 blocks/CU.
__global__ __launch_bounds__(256, 6) void edge_mfma8(
    const float* __restrict__ e,
    const float* __restrict__ qkv,
    const unsigned short* __restrict__ kbf,
    const float* __restrict__ We,   // (64,8)
    const float* __restrict__ Wg,   // (64,8)
    const float* __restrict__ Oe,   // (8,64)
    float* __restrict__ e_out,
    float* __restrict__ pvw,        // (8192, 64)
    float* __restrict__ dngs)       // (8192, 16)
{
    __shared__ float ebuf[4][16][64];             // 16 KB (single-buffered)
    __shared__ float uni[1088];                   // Wl[1024]|Qlds[64] -> E_lds
    __shared__ unsigned short Pl[4][32][8];       // 2 KB, P as bf16
    __shared__ float Oelds[512];                  // 2 KB
    __shared__ float red[256];                    // 1 KB
    __shared__ float wdn[4][8], wgs[4][8];

    float* const Wl = uni;
    float* const Qlds = uni + 1024;
    auto E_lds = reinterpret_cast<float(*)[32][8]>(uni);  // valid after barrier2

    const int t = threadIdx.x, w = t >> 6, l = t & 63;
    const int a2 = l >> 4, m16 = l & 15;
    const int bid = blockIdx.x;
    const int wg = (bid & 7) * 1024 + (bid >> 3);  // XCD-chunked (8192%8==0)
    const int bn = wg >> 2, chunk = wg & 3;
    const int b = bn >> 9;
    const int rowc = chunk * 128 + w * 32;
    const float* __restrict__ Qp = qkv + (size_t)bn * 192;
    const float* __restrict__ ebase = e + (size_t)bn * 32768;
    float* __restrict__ eob = e_out + (size_t)bn * 32768;

#define STAGE_E(s) do {                                                          \
        _Pragma("unroll")                                                        \
        for (int i_ = 0; i_ < 4; ++i_) {                                         \
            const int lrow = i_ * 4 + (l >> 4);                                  \
            gload16f(ebase + (size_t)(rowc + (s) * 16 + lrow) * 64 + (((l & 15) ^ lrow) * 4), \
                     &ebuf[w][i_ * 4][0]);                                       \
        } } while (0)

    // ---- prologue: issue ALL loads before any wait (11 VMEM in fixed order)
    {
        const float* wsrc = (w < 2) ? (We + w * 256) : (Wg + (w - 2) * 256);
        gload16f(wsrc + l * 4, &Wl[w * 256]);                      // 1
        if (l < 16) gload16f(Qp + l * 4, &Qlds[0]);                // 2
        if (l < 32) gload16f(Oe + w * 128 + l * 4, &Oelds[w * 128]); // 3
    }
    STAGE_E(0);                                                    // 4-7
    bf16x8 kr0[2], kr1[2];
    {
        const unsigned short* kb0 = kbf + (size_t)(b * NN + rowc + m16) * 64 + a2 * 16;
        kr0[0] = *(const bf16x8*)(kb0);                            // 8
        kr0[1] = *(const bf16x8*)(kb0 + 8);                        // 9
        kr1[0] = *(const bf16x8*)(kb0 + 1024);                     // 10 (16 rows on)
        kr1[1] = *(const bf16x8*)(kb0 + 1032);                     // 11
    }

    WAITV(8);        // shared 3 retired; e0 + K in flight
    BARRIER();

    // ---- persistent B-fragments from LDS (k = a2*16 + c*8 + j bijection) ----
    const int colbase = (m16 < 8) ? m16 : (504 + m16);
    bf16x8 WB[2], QdB[2];
#pragma unroll
    for (int c = 0; c < 2; ++c) {
        const int head = a2 * 2 + c;
#pragma unroll
        for (int j = 0; j < 8; ++j) {
            const int d = a2 * 16 + c * 8 + j;
            WB[c][j] = (short)bhi16(Wl[d * 8 + colbase]);
            QdB[c][j] = (m16 == head) ? (short)bhi16(Qlds[d]) : (short)0;
        }
    }
    float dn = 0.f, gs = 0.f;
    BARRIER();       // all waves done reading Wl/Qlds; E_lds may now overwrite

#define SLAB(s, KR) do {                                                         \
        f32x4 c1 = {0.f, 0.f, 0.f, 0.f}, c2 = {0.f, 0.f, 0.f, 0.f};             \
        _Pragma("unroll")                                                        \
        for (int c = 0; c < 2; ++c) {                                            \
            const int g0 = a2 * 4 + c * 2;                                       \
            const float4 e0 = *(const float4*)&ebuf[w][m16][((g0 ^ m16) * 4)];   \
            const float4 e1 = *(const float4*)&ebuf[w][m16][(((g0 + 1) ^ m16) * 4)]; \
            bf16x8 ac;                                                           \
            ac[0] = (short)bhi16(e0.x); ac[1] = (short)bhi16(e0.y);              \
            ac[2] = (short)bhi16(e0.z); ac[3] = (short)bhi16(e0.w);              \
            ac[4] = (short)bhi16(e1.x); ac[5] = (short)bhi16(e1.y);              \
            ac[6] = (short)bhi16(e1.z); ac[7] = (short)bhi16(e1.w);              \
            c1 = __builtin_amdgcn_mfma_f32_16x16x32_bf16(ac, WB[c], c1, 0, 0, 0); \
            c2 = __builtin_amdgcn_mfma_f32_16x16x32_bf16(KR[c], QdB[c], c2, 0, 0, 0); \
        }                                                                        \
        if (m16 < 8) {                                                           \
            _Pragma("unroll")                                                    \
            for (int r = 0; r < 4; ++r) {                                        \
                const float E_ = fminf(fmaxf(c2[r] * SCALE, -5.f), 5.f) + c1[r]; \
                const float P_ = __expf(E_ - SMAX);                              \
                dn += P_;                                                        \
                E_lds[w][(s) * 16 + a2 * 4 + r][m16] = E_;                       \
                Pl[w][(s) * 16 + a2 * 4 + r][m16] = bhi16(P_);                   \
            }                                                                    \
        } else {                                                                 \
            _Pragma("unroll")                                                    \
            for (int r = 0; r < 4; ++r) gs += 1.f / (1.f + __expf(-c1[r]));      \
        } } while (0)

    WAITV(4);        // e0 landed (K regs auto-waited by compiler at use)
    SLAB(0, kr0);
    STAGE_E(1);      // single buffer: reissue after slab0 reads
    WAITV(0);
    SLAB(1, kr1);

    // ---- reduce dn/gs across a2-groups ----
    dn += __shfl_xor(dn, 16, 64); dn += __shfl_xor(dn, 32, 64);
    gs += __shfl_xor(gs, 16, 64); gs += __shfl_xor(gs, 32, 64);
    if (a2 == 0 && m16 < 8) wdn[w][m16] = dn;
    if (a2 == 0 && m16 >= 8) wgs[w][m16 - 8] = gs;

    // ---- PV partial over own-wave 32 rows (256B/instr, L2-hot; P from LDS) --
    {
        const int k = l & 7, hh = (l >> 3) & 7;
        const float* vb = qkv + (size_t)(b * NN + rowc) * 192 + 128 + hh * 8 + k;
        float acc = 0.f;
#pragma unroll 8
        for (int i = 0; i < 32; ++i) {
            acc = fmaf(bf2f(Pl[w][i][hh]), vb[(size_t)i * 192], acc);
        }
        red[t] = acc;
    }
    __syncthreads();
    if (t < 64)
        pvw[(size_t)wg * 64 + t] = red[t] + red[64 + t] + red[128 + t] + red[192 + t];
    if (t < 8)
        dngs[(size_t)wg * 16 + t] = wdn[0][t] + wdn[1][t] + wdn[2][t] + wdn[3][t];
    else if (t < 16)
        dngs[(size_t)wg * 16 + t] = wgs[0][t - 8] + wgs[1][t - 8] + wgs[2][t - 8] + wgs[3][t - 8];

    // ---- e_out epilogue from E_lds; Oe coefficients from LDS ----
    {
        const int j4 = l & 15, mr = l >> 4;
        float oc[8][4];
#pragma unroll
        for (int h = 0; h < 8; ++h) {
            const float4 v = *(const float4*)&Oelds[h * 64 + j4 * 4];
            oc[h][0] = v.x; oc[h][1] = v.y; oc[h][2] = v.z; oc[h][3] = v.w;
        }
#pragma unroll 2
        for (int p = 0; p < 8; ++p) {
            const int mloc = p * 4 + mr;
            const float* er = &E_lds[w][mloc][0];
            const float4 ra = *reinterpret_cast<const float4*>(er);
            const float4 rb = *reinterpret_cast<const float4*>(er + 4);
            float o0 = ra.x * oc[0][0], o1 = ra.x * oc[0][1], o2 = ra.x * oc[0][2], o3 = ra.x * oc[0][3];
            o0 = fmaf(ra.y, oc[1][0], o0); o1 = fmaf(ra.y, oc[1][1], o1); o2 = fmaf(ra.y, oc[1][2], o2); o3 = fmaf(ra.y, oc[1][3], o3);
            o0 = fmaf(ra.z, oc[2][0], o0); o1 = fmaf(ra.z, oc[2][1], o1); o2 = fmaf(ra.z, oc[2][2], o2); o3 = fmaf(ra.z, oc[2][3], o3);
            o0 = fmaf(ra.w, oc[3][0], o0); o1 = fmaf(ra.w, oc[3][1], o1); o2 = fmaf(ra.w, oc[3][2], o2); o3 = fmaf(ra.w, oc[3][3], o3);
            o0 = fmaf(rb.x, oc[4][0], o0); o1 = fmaf(rb.x, oc[4][1], o1); o2 = fmaf(rb.x, oc[4][2], o2); o3 = fmaf(rb.x, oc[4][3], o3);
            o0 = fmaf(rb.y, oc[5][0], o0); o1 = fmaf(rb.y, oc[5][1], o1); o2 = fmaf(rb.y, oc[5][2], o2); o3 = fmaf(rb.y, oc[5][3], o3);
            o0 = fmaf(rb.z, oc[6][0], o0); o1 = fmaf(rb.z, oc[6][1], o1); o2 = fmaf(rb.z, oc[6][2], o2); o3 = fmaf(rb.z, oc[6][3], o3);
            o0 = fmaf(rb.w, oc[7][0], o0); o1 = fmaf(rb.w, oc[7][1], o1); o2 = fmaf(rb.w, oc[7][2], o2); o3 = fmaf(rb.w, oc[7][3], o3);
            reinterpret_cast<float4*>(eob + (size_t)(rowc + mloc) * 64 + j4 * 4)[0]
                = make_float4(o0, o1, o2, o3);
        }
    }
#undef STAGE_E
#undef SLAB
}

// ---------------- K3: combine partials -> n_out ----------------
__global__ __launch_bounds__(64) void nout_fin(
    const float* __restrict__ pvw,   // (8192,64)
    const float* __restrict__ dngs,  // (8192,16)
    const float* __restrict__ On,    // (64,64)
    float* __restrict__ n_out)       // (B,N,64)
{
    __shared__ float vfin[64];
    const int bn = blockIdx.x, t = threadIdx.x;
    const int hh = t >> 3;
    float pv = 0.f, den = 0.f, gsum = 0.f;
#pragma unroll
    for (int c = 0; c < 4; ++c) {
        const size_t wg = (size_t)bn * 4 + c;
        pv += pvw[wg * 64 + t];
        den += dngs[wg * 16 + hh];
        gsum += dngs[wg * 16 + 8 + hh];
    }
    vfin[t] = pv * (1.f / den) * log1pf(gsum);
    __syncthreads();
    float acc = 0.f;
#pragma unroll
    for (int i = 0; i < 64; ++i)
        acc = fmaf(vfin[i], On[i * 64 + t], acc);
    n_out[(size_t)bn * 64 + t] = acc;
}

extern "C" void kernel_launch(void* const* d_in, const int* in_sizes, int n_in,
                              void* d_out, int out_size, void* d_ws, size_t ws_size,
                              hipStream_t stream) {
    const float* n_in_p = (const float*)d_in[0];
    const float* e_p    = (const float*)d_in[1];
    const float* Wqkv   = (const float*)d_in[2];
    const float* On     = (const float*)d_in[3];
    const float* Wg     = (const float*)d_in[4];
    const float* We     = (const float*)d_in[5];
    const float* Oe     = (const float*)d_in[6];
    float* out = (float*)d_out;
    float* n_out = out;                              // 4*512*64
    float* e_out = out + (size_t)4 * 512 * 64;       // 4*512*512*64
    float* qkv = (float*)d_ws;                       // 393216 floats
    float* pvw = qkv + 393216;                       // 524288 floats
    float* dngs = pvw + 524288;                      // 131072 floats
    unsigned short* kbf = (unsigned short*)(dngs + 131072);  // 131072 ushorts

    hipLaunchKernelGGL(qkv_proj, dim3(4 * NN), dim3(64), 0, stream, n_in_p, Wqkv, qkv, kbf);
    hipLaunchKernelGGL(edge_mfma8, dim3(8192), dim3(256), 0, stream,
                       e_p, qkv, kbf, We, Wg, Oe, e_out, pvw, dngs);
    hipLaunchKernelGGL(nout_fin, dim3(4 * NN), dim3(64), 0, stream,
                       pvw, dngs, On, n_out);
}

// Round 17
// 150.924 us; speedup vs baseline: 3.1054x; 3.1054x over previous
//
#include <hip/hip_runtime.h>

#define NN 512
#define SCALE 0.35355339059327373f  /* dk^-0.5, dk=8 */
#define SMAX 6.0f                   /* fixed softmax shift (exact ratios) */

typedef short bf16x8 __attribute__((ext_vector_type(8)));
typedef float f32x4 __attribute__((ext_vector_type(4)));

static __device__ __forceinline__ unsigned short bhi16(float x) {
    return (unsigned short)(__float_as_uint(x) >> 16);
}

// ---------------- K1: QKV projection (+ K pre-truncated to bf16) ----------
__global__ __launch_bounds__(64) void qkv_proj(const float* __restrict__ nin,
                                               const float* __restrict__ Wqkv,
                                               float* __restrict__ qkv,
                                               unsigned short* __restrict__ kbf) {
    const int r = blockIdx.x;
    const int j = threadIdx.x;
    const float* nr = nin + (size_t)r * 64;
    float a0 = 0.f, a1 = 0.f, a2 = 0.f;
#pragma unroll
    for (int d = 0; d < 64; ++d) {
        const float nv = nr[d];
        const float* wr = Wqkv + d * 192;
        a0 = fmaf(nv, wr[j], a0);
        a1 = fmaf(nv, wr[64 + j], a1);
        a2 = fmaf(nv, wr[128 + j], a2);
    }
    float* o = qkv + (size_t)r * 192;
    o[j] = a0; o[64 + j] = a1; o[128 + j] = a2;
    kbf[(size_t)r * 64 + j] = bhi16(a1);
}

__device__ __forceinline__ void gload16f(const float* g, float* l) {
    __builtin_amdgcn_global_load_lds(
        (const __attribute__((address_space(1))) unsigned int*)(g),
        (__attribute__((address_space(3))) unsigned int*)(l), 16, 0, 0);
}
__device__ __forceinline__ void gload16u(const unsigned short* g, unsigned short* l) {
    __builtin_amdgcn_global_load_lds(
        (const __attribute__((address_space(1))) unsigned int*)(g),
        (__attribute__((address_space(3))) unsigned int*)(l), 16, 0, 0);
}
#define WAITV(N) asm volatile("s_waitcnt vmcnt(" #N ")" ::: "memory")
#define BARRIER() __builtin_amdgcn_s_barrier()

// ---------------- K2: r15 structure + T14 async reg-staged slab1 ----------
// grid 8192 = (bn, chunk of 128 m-rows). 4 waves; wave owns 32 rows = 2 slabs.
// Slab1 e/K loaded to REGISTERS in the prologue (latency hides under slab0),
// ds_written into the single LDS buffer after slab0's reads. No exposed waits.
__global__ __launch_bounds__(256, 4) void edge_mfma9(
    const float* __restrict__ e,
    const float* __restrict__ qkv,
    const unsigned short* __restrict__ kbf,
    const float* __restrict__ We,   // (64,8)
    const float* __restrict__ Wg,   // (64,8)
    const float* __restrict__ Oe,   // (8,64)
    float* __restrict__ e_out,
    float* __restrict__ pvw,        // (8192, 64)
    float* __restrict__ dngs)       // (8192, 16)
{
    __shared__ float ebuf[4][16][64];             // 16 KB (single-buffered)
    __shared__ unsigned short kbl[4][16][64];     // 8 KB
    __shared__ float uni[1088];                   // Wl[1024]|Qlds[64] -> E_lds
    __shared__ float Oelds[512];                  // 2 KB
    __shared__ float red[256];                    // 1 KB
    __shared__ float wdn[4][8], wgs[4][8];

    float* const Wl = uni;
    float* const Qlds = uni + 1024;
    auto E_lds = reinterpret_cast<float(*)[32][8]>(uni);  // valid after barrier2

    const int t = threadIdx.x, w = t >> 6, l = t & 63;
    const int a2 = l >> 4, m16 = l & 15;
    const int bid = blockIdx.x;
    const int wg = (bid & 7) * 1024 + (bid >> 3);  // XCD-chunked (8192%8==0)
    const int bn = wg >> 2, chunk = wg & 3;
    const int b = bn >> 9;
    const int rowc = chunk * 128 + w * 32;
    const float* __restrict__ Qp = qkv + (size_t)bn * 192;
    const float* __restrict__ ebase = e + (size_t)bn * 32768;
    float* __restrict__ eob = e_out + (size_t)bn * 32768;

    // ---- prologue: ALL VMEM issued before any wait (15 ops, fixed order) ----
    {
        const float* wsrc = (w < 2) ? (We + w * 256) : (Wg + (w - 2) * 256);
        gload16f(wsrc + l * 4, &Wl[w * 256]);                        // 1
        if (l < 16) gload16f(Qp + l * 4, &Qlds[0]);                  // 2
        if (l < 32) gload16f(Oe + w * 128 + l * 4, &Oelds[w * 128]); // 3
    }
    {   // slab0 e -> LDS (4), K0 -> LDS (2)
#pragma unroll
        for (int i = 0; i < 4; ++i) {
            const int lrow = i * 4 + (l >> 4);
            gload16f(ebase + (size_t)(rowc + lrow) * 64 + (((l & 15) ^ lrow) * 4),
                     &ebuf[w][i * 4][0]);                            // 4-7
        }
#pragma unroll
        for (int i = 0; i < 2; ++i) {
            const int r8 = i * 8 + (l >> 3);
            gload16u(kbf + (size_t)(b * NN + rowc + r8) * 64 + (((l & 7) ^ (r8 & 7)) * 8),
                     &kbl[w][i * 8][0]);                             // 8-9
        }
    }
    float4 e1r[4];
    bf16x8 k1r[2];
    {   // slab1 e/K -> REGISTERS (same global addressing as the LDS image)
#pragma unroll
        for (int i = 0; i < 4; ++i) {
            const int lrow = i * 4 + (l >> 4);
            e1r[i] = *(const float4*)(ebase + (size_t)(rowc + 16 + lrow) * 64
                                      + (((l & 15) ^ lrow) * 4));    // 10-13
        }
#pragma unroll
        for (int i = 0; i < 2; ++i) {
            const int r8 = i * 8 + (l >> 3);
            k1r[i] = *(const bf16x8*)(kbf + (size_t)(b * NN + rowc + 16 + r8) * 64
                                      + (((l & 7) ^ (r8 & 7)) * 8)); // 14-15
        }
    }

    WAITV(12);       // retires the 3 shared loads; e0/K0 + reg loads in flight
    BARRIER();

    // ---- persistent B-fragments from LDS ----
    const int colbase = (m16 < 8) ? m16 : (504 + m16);
    bf16x8 WB[2], QdB[2];
#pragma unroll
    for (int c = 0; c < 2; ++c) {
        const int head = c * 4 + a2;
#pragma unroll
        for (int j = 0; j < 8; ++j) {
            const int d = c * 32 + a2 * 8 + j;
            WB[c][j] = (short)bhi16(Wl[d * 8 + colbase]);
            QdB[c][j] = (m16 == head) ? (short)bhi16(Qlds[d]) : (short)0;
        }
    }
    float dn = 0.f, gs = 0.f;
    BARRIER();       // all waves done reading Wl/Qlds; E_lds may now overwrite

#define SLAB(s) do {                                                             \
        f32x4 c1 = {0.f, 0.f, 0.f, 0.f}, c2 = {0.f, 0.f, 0.f, 0.f};             \
        _Pragma("unroll")                                                        \
        for (int c = 0; c < 2; ++c) {                                            \
            const int g0 = c * 8 + a2 * 2;                                       \
            const float4 e0 = *(const float4*)&ebuf[w][m16][((g0 ^ m16) * 4)];   \
            const float4 e1 = *(const float4*)&ebuf[w][m16][(((g0 + 1) ^ m16) * 4)]; \
            bf16x8 ac;                                                           \
            ac[0] = (short)bhi16(e0.x); ac[1] = (short)bhi16(e0.y);              \
            ac[2] = (short)bhi16(e0.z); ac[3] = (short)bhi16(e0.w);              \
            ac[4] = (short)bhi16(e1.x); ac[5] = (short)bhi16(e1.y);              \
            ac[6] = (short)bhi16(e1.z); ac[7] = (short)bhi16(e1.w);              \
            c1 = __builtin_amdgcn_mfma_f32_16x16x32_bf16(ac, WB[c], c1, 0, 0, 0); \
            const bf16x8 kf = *(const bf16x8*)&kbl[w][m16]                       \
                                  [(((c * 4 + a2) ^ (m16 & 7)) * 8)];            \
            c2 = __builtin_amdgcn_mfma_f32_16x16x32_bf16(kf, QdB[c], c2, 0, 0, 0); \
        }                                                                        \
        if (m16 < 8) {                                                           \
            _Pragma("unroll")                                                    \
            for (int r = 0; r < 4; ++r) {                                        \
                const float E_ = fminf(fmaxf(c2[r] * SCALE, -5.f), 5.f) + c1[r]; \
                dn += __expf(E_ - SMAX);                                         \
                E_lds[w][(s) * 16 + a2 * 4 + r][m16] = E_;                       \
            }                                                                    \
        } else {                                                                 \
            _Pragma("unroll")                                                    \
            for (int r = 0; r < 4; ++r) gs += 1.f / (1.f + __expf(-gg_unused_r(c1[r])));  \
        } } while (0)
#define gg_unused_r(x) (-(x))   /* sigmoid(gg): c1 holds gg for m16>=8 */

    WAITV(6);        // e0+K0 landed; slab1 reg loads still in flight
    SLAB(0);
    // ---- write-late: slab1 regs -> LDS (own-wave, DS pipe in-order) ----
#pragma unroll
    for (int i = 0; i < 4; ++i)
        *(float4*)((float*)&ebuf[w][0][0] + i * 256 + l * 4) = e1r[i];
#pragma unroll
    for (int i = 0; i < 2; ++i)
        *(bf16x8*)((unsigned short*)&kbl[w][0][0] + i * 512 + l * 8) = k1r[i];
    SLAB(1);

    // ---- reduce dn/gs across a2-groups ----
    dn += __shfl_xor(dn, 16, 64); dn += __shfl_xor(dn, 32, 64);
    gs += __shfl_xor(gs, 16, 64); gs += __shfl_xor(gs, 32, 64);
    if (a2 == 0 && m16 < 8) wdn[w][m16] = dn;
    if (a2 == 0 && m16 >= 8) wgs[w][m16 - 8] = gs;

    // ---- PV partial over own-wave 32 rows (256B/instr, L2-hot) ----
    {
        const int k = l & 7, hh = (l >> 3) & 7;
        const float* vb = qkv + (size_t)(b * NN + rowc) * 192 + 128 + hh * 8 + k;
        float acc = 0.f;
#pragma unroll 8
        for (int i = 0; i < 32; ++i) {
            const float p = __expf(E_lds[w][i][hh] - SMAX);
            acc = fmaf(p, vb[(size_t)i * 192], acc);
        }
        red[t] = acc;
    }
    __syncthreads();
    if (t < 64)
        pvw[(size_t)wg * 64 + t] = red[t] + red[64 + t] + red[128 + t] + red[192 + t];
    if (t < 8)
        dngs[(size_t)wg * 16 + t] = wdn[0][t] + wdn[1][t] + wdn[2][t] + wdn[3][t];
    else if (t < 16)
        dngs[(size_t)wg * 16 + t] = wgs[0][t - 8] + wgs[1][t - 8] + wgs[2][t - 8] + wgs[3][t - 8];

    // ---- e_out epilogue from E_lds; Oe coefficients from LDS ----
    {
        const int j4 = l & 15, mr = l >> 4;
        float oc[8][4];
#pragma unroll
        for (int h = 0; h < 8; ++h) {
            const float4 v = *(const float4*)&Oelds[h * 64 + j4 * 4];
            oc[h][0] = v.x; oc[h][1] = v.y; oc[h][2] = v.z; oc[h][3] = v.w;
        }
#pragma unroll 2
        for (int p = 0; p < 8; ++p) {
            const int mloc = p * 4 + mr;
            const float* er = &E_lds[w][mloc][0];
            const float4 ra = *reinterpret_cast<const float4*>(er);
            const float4 rb = *reinterpret_cast<const float4*>(er + 4);
            float o0 = ra.x * oc[0][0], o1 = ra.x * oc[0][1], o2 = ra.x * oc[0][2], o3 = ra.x * oc[0][3];
            o0 = fmaf(ra.y, oc[1][0], o0); o1 = fmaf(ra.y, oc[1][1], o1); o2 = fmaf(ra.y, oc[1][2], o2); o3 = fmaf(ra.y, oc[1][3], o3);
            o0 = fmaf(ra.z, oc[2][0], o0); o1 = fmaf(ra.z, oc[2][1], o1); o2 = fmaf(ra.z, oc[2][2], o2); o3 = fmaf(ra.z, oc[2][3], o3);
            o0 = fmaf(ra.w, oc[3][0], o0); o1 = fmaf(ra.w, oc[3][1], o1); o2 = fmaf(ra.w, oc[3][2], o2); o3 = fmaf(ra.w, oc[3][3], o3);
            o0 = fmaf(rb.x, oc[4][0], o0); o1 = fmaf(rb.x, oc[4][1], o1); o2 = fmaf(rb.x, oc[4][2], o2); o3 = fmaf(rb.x, oc[4][3], o3);
            o0 = fmaf(rb.y, oc[5][0], o0); o1 = fmaf(rb.y, oc[5][1], o1); o2 = fmaf(rb.y, oc[5][2], o2); o3 = fmaf(rb.y, oc[5][3], o3);
            o0 = fmaf(rb.z, oc[6][0], o0); o1 = fmaf(rb.z, oc[6][1], o1); o2 = fmaf(rb.z, oc[6][2], o2); o3 = fmaf(rb.z, oc[6][3], o3);
            o0 = fmaf(rb.w, oc[7][0], o0); o1 = fmaf(rb.w, oc[7][1], o1); o2 = fmaf(rb.w, oc[7][2], o2); o3 = fmaf(rb.w, oc[7][3], o3);
            reinterpret_cast<float4*>(eob + (size_t)(rowc + mloc) * 64 + j4 * 4)[0]
                = make_float4(o0, o1, o2, o3);
        }
    }
#undef SLAB
#undef gg_unused_r
}

// ---------------- K3: combine partials -> n_out ----------------
__global__ __launch_bounds__(64) void nout_fin(
    const float* __restrict__ pvw,   // (8192,64)
    const float* __restrict__ dngs,  // (8192,16)
    const float* __restrict__ On,    // (64,64)
    float* __restrict__ n_out)       // (B,N,64)
{
    __shared__ float vfin[64];
    const int bn = blockIdx.x, t = threadIdx.x;
    const int hh = t >> 3;
    float pv = 0.f, den = 0.f, gsum = 0.f;
#pragma unroll
    for (int c = 0; c < 4; ++c) {
        const size_t wg = (size_t)bn * 4 + c;
        pv += pvw[wg * 64 + t];
        den += dngs[wg * 16 + hh];
        gsum += dngs[wg * 16 + 8 + hh];
    }
    vfin[t] = pv * (1.f / den) * log1pf(gsum);
    __syncthreads();
    float acc = 0.f;
#pragma unroll
    for (int i = 0; i < 64; ++i)
        acc = fmaf(vfin[i], On[i * 64 + t], acc);
    n_out[(size_t)bn * 64 + t] = acc;
}

extern "C" void kernel_launch(void* const* d_in, const int* in_sizes, int n_in,
                              void* d_out, int out_size, void* d_ws, size_t ws_size,
                              hipStream_t stream) {
    const float* n_in_p = (const float*)d_in[0];
    const float* e_p    = (const float*)d_in[1];
    const float* Wqkv   = (const float*)d_in[2];
    const float* On     = (const float*)d_in[3];
    const float* Wg     = (const float*)d_in[4];
    const float* We     = (const float*)d_in[5];
    const float* Oe     = (const float*)d_in[6];
    float* out = (float*)d_out;
    float* n_out = out;                              // 4*512*64
    float* e_out = out + (size_t)4 * 512 * 64;       // 4*512*512*64
    float* qkv = (float*)d_ws;                       // 393216 floats
    float* pvw = qkv + 393216;                       // 524288 floats
    float* dngs = pvw + 524288;                      // 131072 floats
    unsigned short* kbf = (unsigned short*)(dngs + 131072);  // 131072 ushorts

    hipLaunchKernelGGL(qkv_proj, dim3(4 * NN), dim3(64), 0, stream, n_in_p, Wqkv, qkv, kbf);
    hipLaunchKernelGGL(edge_mfma9, dim3(8192), dim3(256), 0, stream,
                       e_p, qkv, kbf, We, Wg, Oe, e_out, pvw, dngs);
    hipLaunchKernelGGL(nout_fin, dim3(4 * NN), dim3(64), 0, stream,
                       pvw, dngs, On, n_out);
}